// Round 2
// baseline (514.537 us; speedup 1.0000x reference)
//
#include <hip/hip_runtime.h>

#define B 256
#define S 197
#define D 768
#define P 20
#define L 5
#define T 10
#define K 5

// Output element offsets (float32, concatenated in return order)
#define ROWS_PE 272                     // (T+K)*L + S = 75 + 197
#define SZ_PE   (B * ROWS_PE * D)       // 53,477,376
#define OFF_RS  ((long)SZ_PE)           // reduce_sim scalar
#define OFF_TOK (OFF_RS + 1)            // tokens [B,75,D] — 4B-aligned only!
#define SZ_TOK  (B * (T + K) * L * D)   // 14,745,600
#define OFF_IDX (OFF_TOK + SZ_TOK)      // idx_pruned [B,K] as float
#define OFF_XN  (OFF_IDX + B * K)       // x_norm [B,D]

#define NPROD   (4 * B)                 // 1024 producer blocks (b*4+tile)
#define NASSIST 9600                    // B*50*192 f4 items / 256

typedef float f4 __attribute__((ext_vector_type(4)));

// Single fused kernel, grid = NPROD + NASSIST blocks of 256.
//  blocks [0,NPROD):  producer for (b=blk>>2, tile=blk&3): stream x_embed rows
//                     into pe rows [75,272) (NT), accumulate per-tile partial
//                     column sums. Then device-scope fetch_add(tile_done[b]);
//                     the LAST tile finisher becomes the consumer for b:
//                     mean->norm->sim->top-k->selected rows->done-counter.
//                     No spinning anywhere; liveness never depends on order.
//  blocks [NPROD,..): stream assist rows into pe rows [0,50) + tok (NT).
__global__ void __launch_bounds__(256)
k_all(const float* __restrict__ x, const float* __restrict__ prompt,
      const float* __restrict__ pkey, const float* __restrict__ assist,
      float* __restrict__ pe, float* __restrict__ tok,
      float* __restrict__ xnorm_out, float* __restrict__ idxp_f,
      float* __restrict__ partial, float* __restrict__ xsum,
      int* __restrict__ keycnt, unsigned* __restrict__ tile_done,
      unsigned* __restrict__ done, float* __restrict__ rs) {
    const int t = threadIdx.x;              // 0..255
    const int blk = blockIdx.x;

    if (blk >= NPROD) {
        // ---- assist copy: 256 consecutive float4 items of the (b,j,c) space
        const int item = (blk - NPROD) * 256 + t;      // < B*50*192
        const int b = item / 9600;                     // 50*192 items per b
        const int r = item - b * 9600;
        const int j = r / 192;                         // assist row 0..49
        const int c = r - j * 192;
        const f4 v = ((const f4*)assist)[j * 192 + c];
        __builtin_nontemporal_store(v, (f4*)pe + ((long)b * ROWS_PE + j) * 192 + c);
        float* d2 = tok + ((long)b * 75 + j) * 768 + 4 * c;   // 4B-aligned region
        __builtin_nontemporal_store(v[0], d2 + 0);
        __builtin_nontemporal_store(v[1], d2 + 1);
        __builtin_nontemporal_store(v[2], d2 + 2);
        __builtin_nontemporal_store(v[3], d2 + 3);
        return;
    }

    // ---- producer: (b, tile), threads 0..191 own f4 columns
    const int b = blk >> 2;
    const int tile = blk & 3;
    if (t < 192) {
        const int s0 = tile * 50;
        const int s1 = (s0 + 50 < S) ? s0 + 50 : S;
        const f4* x4 = (const f4*)x;
        f4* o4 = (f4*)pe;
        const int xbase = b * S * 192 + t;
        const int obase = (b * ROWS_PE + (T + K) * L) * 192 + t;
        f4 acc = {0.f, 0.f, 0.f, 0.f};
        for (int s = s0; s < s1; ++s) {
            f4 v = __builtin_nontemporal_load(x4 + xbase + s * 192);
            acc += v;
            __builtin_nontemporal_store(v, o4 + obase + s * 192);
        }
        ((f4*)partial)[blk * 192 + t] = acc;    // normal store — re-read soon
    }

    __shared__ int winner;
    __syncthreads();                            // all partial stores drained (vmcnt 0)
    if (t == 0) {
        __threadfence();                        // agent release: L2 writeback
        const unsigned prev = __hip_atomic_fetch_add(
            &tile_done[b], 1u, __ATOMIC_ACQ_REL, __HIP_MEMORY_SCOPE_AGENT);
        winner = (prev == 3u) ? 1 : 0;          // acquire: cache invalidate
    }
    __syncthreads();
    if (!winner) return;

    // ---- consumer: this block saw all 4 tiles complete
    const int lane = t & 63, wid = t >> 6;
    __shared__ float xs[D];
    __shared__ float sim[P];
    __shared__ float red[4];
    __shared__ float coef[P];
    __shared__ int sidx[K];
    __shared__ int amLast;

    // x_mean -> x_norm for columns t, t+256, t+512 (fixed tile order = deterministic)
    float v0 = 0.f, v1 = 0.f, v2 = 0.f;
    for (int tl = 0; tl < 4; ++tl) {
        float* pp = partial + (b * 4 + tl) * D;
        v0 += __hip_atomic_load(pp + t,       __ATOMIC_RELAXED, __HIP_MEMORY_SCOPE_AGENT);
        v1 += __hip_atomic_load(pp + t + 256, __ATOMIC_RELAXED, __HIP_MEMORY_SCOPE_AGENT);
        v2 += __hip_atomic_load(pp + t + 512, __ATOMIC_RELAXED, __HIP_MEMORY_SCOPE_AGENT);
    }
    const float invS = 1.0f / (float)S;
    v0 *= invS; v1 *= invS; v2 *= invS;
    float ss = v0 * v0 + v1 * v1 + v2 * v2;
    for (int o = 32; o > 0; o >>= 1) ss += __shfl_down(ss, o);
    if (lane == 0) red[wid] = ss;
    __syncthreads();
    if (t == 0) red[0] = rsqrtf(fmaxf(red[0] + red[1] + red[2] + red[3], 1e-12f));
    __syncthreads();
    const float rn = red[0];
    v0 *= rn; v1 *= rn; v2 *= rn;
    xs[t] = v0; xs[t + 256] = v1; xs[t + 512] = v2;
    xnorm_out[b * D + t] = v0;                  // OFF_XN is odd -> scalar stores
    xnorm_out[b * D + t + 256] = v1;
    xnorm_out[b * D + t + 512] = v2;
    atomicAdd(&xsum[t], v0);
    atomicAdd(&xsum[t + 256], v1);
    atomicAdd(&xsum[t + 512], v2);
    __syncthreads();

    // similarities: wave `wid` handles prompts wid, wid+4, ...
    for (int p = wid; p < P; p += 4) {
        const float* pr = pkey + p * D;
        float axk = 0.f, akk = 0.f;
        for (int d = lane; d < D; d += 64) {
            const float kv = pr[d];
            axk += xs[d] * kv;
            akk += kv * kv;
        }
        for (int o = 32; o > 0; o >>= 1) {
            axk += __shfl_down(axk, o);
            akk += __shfl_down(akk, o);
        }
        if (lane == 0) sim[p] = axk * rsqrtf(fmaxf(akk, 1e-12f));
    }
    __syncthreads();

    // serial top-K (strict >, ascending scan = jax stable ties)
    if (t == 0) {
        unsigned usedMask = 0u;
        for (int k = 0; k < K; ++k) {
            float best = -INFINITY; int bi = 0;
            for (int p = 0; p < P; ++p)
                if (!((usedMask >> p) & 1u) && sim[p] > best) { best = sim[p]; bi = p; }
            usedMask |= 1u << bi;
            const int oi = (best > 0.0f) ? bi : -1;
            sidx[k] = oi;
            idxp_f[b * K + k] = (float)oi;
            if (oi >= 0) atomicAdd(&keycnt[bi], 1);
        }
    }
    __syncthreads();

    // selected rows -> pe rows [50,75) + tok rows [50,75)
    for (int it = t; it < K * L * 192; it += 256) {
        const int j = it / 192;                 // 0..24
        const int c = it - j * 192;
        const int k = j / L;
        const int l = j - k * L;
        const int idx = sidx[k];
        f4 v = {0.f, 0.f, 0.f, 0.f};
        if (idx >= 0) v = ((const f4*)prompt)[(idx * L + l) * 192 + c];
        __builtin_nontemporal_store(v, (f4*)pe + ((long)b * ROWS_PE + T * L + j) * 192 + c);
        float* d2 = tok + ((long)b * 75 + T * L + j) * 768 + 4 * c;
        __builtin_nontemporal_store(v[0], d2 + 0);
        __builtin_nontemporal_store(v[1], d2 + 1);
        __builtin_nontemporal_store(v[2], d2 + 2);
        __builtin_nontemporal_store(v[3], d2 + 3);
    }

    // last consumer computes reduce_sim = xsum . (sum_p cnt_p*rsqrt(|k_p|^2)*k_p)/B
    if (t == 0) {
        __threadfence();
        const unsigned prev =
            __hip_atomic_fetch_add(done, 1u, __ATOMIC_ACQ_REL, __HIP_MEMORY_SCOPE_AGENT);
        amLast = (prev == (unsigned)(B - 1)) ? 1 : 0;
    }
    __syncthreads();
    if (amLast) {
        for (int p = wid; p < P; p += 4) {
            const float* pr = pkey + p * D;
            float akk = 0.f;
            for (int d = lane; d < D; d += 64) { const float kv = pr[d]; akk += kv * kv; }
            for (int o = 32; o > 0; o >>= 1) akk += __shfl_down(akk, o);
            if (lane == 0) {
                const int cnt =
                    __hip_atomic_load(&keycnt[p], __ATOMIC_RELAXED, __HIP_MEMORY_SCOPE_AGENT);
                coef[p] = (float)cnt * rsqrtf(fmaxf(akk, 1e-12f));
            }
        }
        __syncthreads();
        float acc = 0.f;
        for (int cc = 0; cc < 3; ++cc) {
            const int d = t + cc * 256;
            float kt = 0.f;
            for (int p = 0; p < P; ++p) kt += coef[p] * pkey[p * D + d];
            const float xv =
                __hip_atomic_load(&xsum[d], __ATOMIC_RELAXED, __HIP_MEMORY_SCOPE_AGENT);
            acc += xv * kt;
        }
        for (int o = 32; o > 0; o >>= 1) acc += __shfl_down(acc, o);
        if (lane == 0) red[wid] = acc;
        __syncthreads();
        if (t == 0) rs[0] = (red[0] + red[1] + red[2] + red[3]) * (1.0f / (float)B);
    }
}

extern "C" void kernel_launch(void* const* d_in, const int* in_sizes, int n_in,
                              void* d_out, int out_size, void* d_ws, size_t ws_size,
                              hipStream_t stream) {
    const float* x      = (const float*)d_in[0];   // [B,S,D]
    const float* prompt = (const float*)d_in[1];   // [P,L,D]
    const float* pkey   = (const float*)d_in[2];   // [P,D]
    const float* assist = (const float*)d_in[3];   // [T,L,D]
    float* out = (float*)d_out;
    float* ws  = (float*)d_ws;

    float*    partial   = ws;                              // 4*B*D floats
    int*      keycnt    = (int*)(partial + 4 * B * D);     // P ints      (zeroed)
    float*    xsum      = (float*)(keycnt + P);            // D floats    (zeroed)
    unsigned* done      = (unsigned*)(xsum + D);           // 1 uint      (zeroed)
    unsigned* tile_done = done + 1;                        // B uints     (zeroed)

    hipMemsetAsync(keycnt, 0, (P + D + 1 + B) * sizeof(float), stream);

    k_all<<<dim3(NPROD + NASSIST), 256, 0, stream>>>(
        x, prompt, pkey, assist, out, out + OFF_TOK, out + OFF_XN, out + OFF_IDX,
        partial, xsum, keycnt, tile_done, done, out + OFF_RS);
}

// Round 4
// 443.505 us; speedup vs baseline: 1.1602x; 1.1602x over previous
//
#include <hip/hip_runtime.h>

#define B 256
#define S 197
#define D 768
#define P 20
#define L 5
#define T 10
#define K 5

// Output element offsets (float32, concatenated in return order)
#define ROWS_PE 272                     // (T+K)*L + S = 75 + 197
#define SZ_PE   (B * ROWS_PE * D)       // 53,477,376
#define OFF_RS  ((long)SZ_PE)           // reduce_sim scalar
#define OFF_TOK (OFF_RS + 1)            // tokens [B,75,D] — 4B-aligned only!
#define SZ_TOK  (B * (T + K) * L * D)   // 14,745,600
#define OFF_IDX (OFF_TOK + SZ_TOK)      // idx_pruned [B,K] as float
#define OFF_XN  (OFF_IDX + B * K)       // x_norm [B,D]

typedef float f4  __attribute__((ext_vector_type(4)));
typedef float f4u __attribute__((ext_vector_type(4), aligned(4)));  // 4B-aligned dwordx4

// Kernel 1: stream x_embed once — copy into prompted_embedding rows [75,272)
// and accumulate per-(b,tile) partial column sums for the mean.
// grid 4*B+1, block 384: threads <192 take even rows of the tile, >=192 odd
// rows (2x the in-flight NT loads per CU vs 192-thread blocks); LDS pair-sum
// keeps the 4-tile deterministic partial layout. Block 4*B zeroes the small
// reduction state (replaces the hipMemsetAsync dispatch; kernel boundary
// orders it before k_fuse's atomics).
__global__ void __launch_bounds__(384)
k_stream(const float* __restrict__ x, float* __restrict__ pe,
         float* __restrict__ partial, unsigned* __restrict__ zstate) {
    const int t = threadIdx.x;
    const int blk = blockIdx.x;
    if (blk == 4 * B) {
        for (int i = t; i < P + D + 1; i += 384) zstate[i] = 0u;  // keycnt,xsum,done
        return;
    }
    const int b = blk >> 2;
    const int tile = blk & 3;
    const int half = (t >= 192) ? 1 : 0;
    const int c = t - half * 192;           // f4 column 0..191
    const int s0 = tile * 50;
    const int s1 = (s0 + 50 < S) ? s0 + 50 : S;
    const f4* x4 = (const f4*)x;
    f4* o4 = (f4*)pe;
    const int xbase = b * S * 192 + c;
    const int obase = (b * ROWS_PE + (T + K) * L) * 192 + c;
    f4 acc = {0.f, 0.f, 0.f, 0.f};
    for (int s = s0 + half; s < s1; s += 2) {
        f4 v = __builtin_nontemporal_load(x4 + xbase + s * 192);
        acc += v;
        __builtin_nontemporal_store(v, o4 + obase + s * 192);
    }
    __shared__ f4 lds[192];
    if (half) lds[c] = acc;
    __syncthreads();
    if (!half) {
        acc += lds[c];
        ((f4*)partial)[blk * 192 + c] = acc;    // normal store — re-read by k_fuse
    }
}

// Kernel 2 (fused): grid = B + 9600 blocks of 256.
//  blocks [0,B):    reduce partial -> x_mean -> x_norm; sim; serial top-K
//                   (jax tie semantics: strict >, ascending scan); write the
//                   K*L selected token rows into pe rows [50,75) + tok;
//                   last finished block computes reduce_sim.
//  blocks [B,..):   stream the T*L assist rows into pe rows [0,50) + tok —
//                   independent of top-k, overlaps with the latency-bound path.
__global__ void __launch_bounds__(256)
k_fuse(const float* __restrict__ partial, const float* __restrict__ pkey,
       const float* __restrict__ prompt, const float* __restrict__ assist,
       float* __restrict__ pe, float* __restrict__ tok,
       float* __restrict__ xnorm_out, float* __restrict__ idxp_f,
       float* __restrict__ xsum, int* __restrict__ keycnt,
       unsigned int* __restrict__ done, float* __restrict__ rs) {
    const int t = threadIdx.x;              // 0..255

    if (blockIdx.x >= B) {
        // ---- assist copy: 256 consecutive float4 items of the (b,j,c) space
        const int item = (blockIdx.x - B) * 256 + t;   // < B*50*192 = 2,457,600
        const int b = item / 9600;                     // 50*192 items per b
        const int r = item - b * 9600;
        const int j = r / 192;                         // assist row 0..49
        const int c = r - j * 192;
        const f4 v = ((const f4*)assist)[j * 192 + c];
        __builtin_nontemporal_store(v, (f4*)pe + ((long)b * ROWS_PE + j) * 192 + c);
        float* d2 = tok + ((long)b * 75 + j) * 768 + 4 * c;   // 4B-aligned region
        f4u vu = v;
        __builtin_nontemporal_store(vu, (f4u*)d2);
        return;
    }

    const int b = blockIdx.x;
    const int lane = t & 63, wid = t >> 6;
    __shared__ float xs[D];
    __shared__ float sim[P];
    __shared__ float red[4];
    __shared__ float coef[P];
    __shared__ int sidx[K];
    __shared__ int amLast;

    // ---- x_mean -> x_norm for columns t, t+256, t+512 (fixed tile order)
    float v0 = 0.f, v1 = 0.f, v2 = 0.f;
    for (int tile = 0; tile < 4; ++tile) {
        const float* pp = partial + (b * 4 + tile) * D;
        v0 += pp[t]; v1 += pp[t + 256]; v2 += pp[t + 512];
    }
    const float invS = 1.0f / (float)S;
    v0 *= invS; v1 *= invS; v2 *= invS;
    float ss = v0 * v0 + v1 * v1 + v2 * v2;
    for (int o = 32; o > 0; o >>= 1) ss += __shfl_down(ss, o);
    if (lane == 0) red[wid] = ss;
    __syncthreads();
    if (t == 0) red[0] = rsqrtf(fmaxf(red[0] + red[1] + red[2] + red[3], 1e-12f));
    __syncthreads();
    const float rn = red[0];
    v0 *= rn; v1 *= rn; v2 *= rn;
    xs[t] = v0; xs[t + 256] = v1; xs[t + 512] = v2;
    xnorm_out[b * D + t] = v0;                  // OFF_XN is odd -> scalar stores
    xnorm_out[b * D + t + 256] = v1;
    xnorm_out[b * D + t + 512] = v2;
    atomicAdd(&xsum[t], v0);
    atomicAdd(&xsum[t + 256], v1);
    atomicAdd(&xsum[t + 512], v2);
    __syncthreads();

    // ---- similarities: wave `wid` handles prompts wid, wid+4, ...
    for (int p = wid; p < P; p += 4) {
        const float* pr = pkey + p * D;
        float axk = 0.f, akk = 0.f;
        for (int d = lane; d < D; d += 64) {
            const float kv = pr[d];
            axk += xs[d] * kv;
            akk += kv * kv;
        }
        for (int o = 32; o > 0; o >>= 1) {
            axk += __shfl_down(axk, o);
            akk += __shfl_down(akk, o);
        }
        if (lane == 0) sim[p] = axk * rsqrtf(fmaxf(akk, 1e-12f));
    }
    __syncthreads();

    // ---- serial top-K (strict >, ascending scan = jax stable ties)
    if (t == 0) {
        unsigned usedMask = 0u;
        for (int k = 0; k < K; ++k) {
            float best = -INFINITY; int bi = 0;
            for (int p = 0; p < P; ++p)
                if (!((usedMask >> p) & 1u) && sim[p] > best) { best = sim[p]; bi = p; }
            usedMask |= 1u << bi;
            const int oi = (best > 0.0f) ? bi : -1;
            sidx[k] = oi;
            idxp_f[b * K + k] = (float)oi;
            if (oi >= 0) atomicAdd(&keycnt[bi], 1);
        }
    }
    __syncthreads();

    // ---- selected rows -> pe rows [50,75) + tok rows [50,75)
    for (int it = t; it < K * L * 192; it += 256) {
        const int j = it / 192;                 // 0..24
        const int c = it - j * 192;
        const int k = j / L;
        const int l = j - k * L;
        const int idx = sidx[k];
        f4 v = {0.f, 0.f, 0.f, 0.f};
        if (idx >= 0) v = ((const f4*)prompt)[(idx * L + l) * 192 + c];
        __builtin_nontemporal_store(v, (f4*)pe + ((long)b * ROWS_PE + T * L + j) * 192 + c);
        float* d2 = tok + ((long)b * 75 + T * L + j) * 768 + 4 * c;
        f4u vu = v;
        __builtin_nontemporal_store(vu, (f4u*)d2);
    }

    // ---- last block computes reduce_sim = xsum . (sum_p cnt_p*rsqrt(|k_p|^2)*k_p)/B
    if (t == 0) {
        __threadfence();
        const unsigned prev =
            __hip_atomic_fetch_add(done, 1u, __ATOMIC_ACQ_REL, __HIP_MEMORY_SCOPE_AGENT);
        amLast = (prev == (unsigned)(B - 1)) ? 1 : 0;
    }
    __syncthreads();
    if (amLast) {
        for (int p = wid; p < P; p += 4) {
            const float* pr = pkey + p * D;
            float akk = 0.f;
            for (int d = lane; d < D; d += 64) { const float kv = pr[d]; akk += kv * kv; }
            for (int o = 32; o > 0; o >>= 1) akk += __shfl_down(akk, o);
            if (lane == 0) {
                const int cnt =
                    __hip_atomic_load(&keycnt[p], __ATOMIC_RELAXED, __HIP_MEMORY_SCOPE_AGENT);
                coef[p] = (float)cnt * rsqrtf(fmaxf(akk, 1e-12f));
            }
        }
        __syncthreads();
        float acc = 0.f;
        for (int cc = 0; cc < 3; ++cc) {
            const int d = t + cc * 256;
            float kt = 0.f;
            for (int p = 0; p < P; ++p) kt += coef[p] * pkey[p * D + d];
            const float xv =
                __hip_atomic_load(&xsum[d], __ATOMIC_RELAXED, __HIP_MEMORY_SCOPE_AGENT);
            acc += xv * kt;
        }
        for (int o = 32; o > 0; o >>= 1) acc += __shfl_down(acc, o);
        if (lane == 0) red[wid] = acc;
        __syncthreads();
        if (t == 0) rs[0] = (red[0] + red[1] + red[2] + red[3]) * (1.0f / (float)B);
    }
}

extern "C" void kernel_launch(void* const* d_in, const int* in_sizes, int n_in,
                              void* d_out, int out_size, void* d_ws, size_t ws_size,
                              hipStream_t stream) {
    const float* x      = (const float*)d_in[0];   // [B,S,D]
    const float* prompt = (const float*)d_in[1];   // [P,L,D]
    const float* pkey   = (const float*)d_in[2];   // [P,D]
    const float* assist = (const float*)d_in[3];   // [T,L,D]
    float* out = (float*)d_out;
    float* ws  = (float*)d_ws;

    // ws layout: partial | keycnt(P) xsum(D) done(1)  — the latter zeroed by k_stream
    float*    partial = ws;                              // 4*B*D floats
    int*      keycnt  = (int*)(partial + 4 * B * D);     // P ints
    float*    xsum    = (float*)(keycnt + P);            // D floats
    unsigned* done    = (unsigned*)(xsum + D);           // 1 uint

    k_stream<<<dim3(4 * B + 1), 384, 0, stream>>>(x, out, partial, (unsigned*)keycnt);
    k_fuse<<<dim3(B + 9600), 256, 0, stream>>>(partial, pkey, prompt, assist,
                                               out, out + OFF_TOK,
                                               out + OFF_XN, out + OFF_IDX,
                                               xsum, keycnt, done, out + OFF_RS);
}